// Round 1
// baseline (455.313 us; speedup 1.0000x reference)
//
#include <hip/hip_runtime.h>

// Swin shifted-window attention, fused. B=32, C=256, H=W=64, WIN=8, SHIFT=4,
// HEADS=8, HD=32, N=64 tokens/window. One block (4 waves) per window.
// bf16 MFMA 16x16x32 for QKV GEMM, S=QK^T, and PV. fp32 accumulate.

typedef __attribute__((ext_vector_type(8))) short short8;   // 8 x bf16 (4 VGPR)
typedef __attribute__((ext_vector_type(4))) float f32x4;

static __device__ __forceinline__ short f2bf(float f) {
    unsigned u = __float_as_uint(f);
    u = (u + 0x7fffu + ((u >> 16) & 1u)) >> 16;   // round-to-nearest-even
    return (short)u;
}

static __device__ __forceinline__ int region(int i) {
    // shift-mask region along one axis: [0,56)=0, [56,60)=1, [60,64)=2
    return (i < 56) ? 0 : ((i < 60) ? 1 : 2);
}

// Prologue: qkv_w fp32 [k=256][col=768] -> Wt bf16 [col=768][k=256] in d_ws.
__global__ void wt_transpose(const float* __restrict__ w, unsigned short* __restrict__ wt) {
    int col = blockIdx.x;      // 0..767
    int k   = threadIdx.x;     // 0..255
    float v = w[k * 768 + col];
    unsigned u = __float_as_uint(v);
    u = (u + 0x7fffu + ((u >> 16) & 1u)) >> 16;
    wt[col * 256 + k] = (unsigned short)u;
}

__global__ __launch_bounds__(256, 2) void swin_kernel(
    const float* __restrict__ x,            // (32,256,64,64)
    const unsigned short* __restrict__ wt,  // bf16 (768,256) transposed weights
    const float* __restrict__ qkv_b,        // (768,)
    const float* __restrict__ tbl,          // (225,8) rel-pos bias table
    float* __restrict__ out)                // (32,256,64,64)
{
    // LDS layout (bytes), total exactly 65536 (2 blocks/CU of 160K):
    //   w_s : 0      .. 50688   (96 x 264 bf16)  B-operand weights for one head
    //   q_s : 50688  .. 55808   (64 x 40 bf16)
    //   k_s : 55808  .. 60928   (64 x 40 bf16)
    //   vt_s: 60928  .. 65536   (32 x 72 bf16)   V transposed [hd][token]
    //   p_s : alias w_s @0      (64 x 72 bf16)   softmax probs
    //   o_s : alias w_s @16384  (64 x 33 f32)    PV output staging
    __shared__ char smem[65536];
    unsigned short* w_s  = (unsigned short*)(smem);
    unsigned short* q_s  = (unsigned short*)(smem + 50688);
    unsigned short* k_s  = (unsigned short*)(smem + 55808);
    unsigned short* vt_s = (unsigned short*)(smem + 60928);
    unsigned short* p_s  = (unsigned short*)(smem);
    float*          o_s  = (float*)(smem + 16384);

    const int tid  = threadIdx.x;
    const int wave = tid >> 6;
    const int lane = tid & 63;
    const int ln   = lane & 15;
    const int quad = lane >> 4;

    const int blk = blockIdx.x;
    const int b  = blk >> 6;          // image
    const int wh = (blk >> 3) & 7;    // window row
    const int ww = blk & 7;           // window col

    // ---- A fragments: this wave's 16 tokens x 256 channels, bf16, in regs.
    // A[m=lane&15][k=quad*8+j]; token = wave*16 + ln. Read once, reuse 8 heads.
    {
    }
    const int t_a  = wave * 16 + ln;
    const int ti_a = t_a >> 3, tj_a = t_a & 7;
    const int si = (wh * 8 + ti_a + 4) & 63;   // roll(-SHIFT) source row
    const int sj = (ww * 8 + tj_a + 4) & 63;
    const float* xb = x + ((size_t)b * 256) * 4096 + si * 64 + sj;
    short8 afrag[8];
    #pragma unroll
    for (int ks = 0; ks < 8; ++ks) {
        #pragma unroll
        for (int j = 0; j < 8; ++j) {
            int c = ks * 32 + quad * 8 + j;
            afrag[ks][j] = f2bf(xb[(size_t)c * 4096]);
        }
    }

    const int row0 = wave * 16 + quad * 4;   // C/D layout: row = quad*4+reg

    for (int h = 0; h < 8; ++h) {
        __syncthreads();   // protect w_s/p_s/o_s from previous phase readers

        // ---- stage 96 weight cols (q|k|v of head h) into w_s[col][k], padded
        #pragma unroll
        for (int i = 0; i < 12; ++i) {
            int idx = i * 256 + tid;              // 0..3071
            int cl  = idx >> 5;                   // local col 0..95
            int ch  = idx & 31;                   // k-chunk (8 elems)
            int col = ((cl >> 5) << 8) + (h << 5) + (cl & 31);  // global col
            short8 wv = *(const short8*)(wt + col * 256 + ch * 8);
            *(short8*)(w_s + cl * 264 + ch * 8) = wv;
        }
        __syncthreads();

        // ---- GEMM1: (64 tok x 256) @ (256 x 96) -> QKV of head h
        f32x4 acc[6];
        #pragma unroll
        for (int jt = 0; jt < 6; ++jt) acc[jt] = (f32x4){0.f, 0.f, 0.f, 0.f};
        #pragma unroll
        for (int ks = 0; ks < 8; ++ks) {
            short8 a = afrag[ks];
            #pragma unroll
            for (int jt = 0; jt < 6; ++jt) {
                short8 bb = *(const short8*)(w_s + (jt * 16 + ln) * 264 + ks * 32 + quad * 8);
                acc[jt] = __builtin_amdgcn_mfma_f32_16x16x32_bf16(a, bb, acc[jt], 0, 0, 0);
            }
        }
        // epilogue: +bias; q scaled; q/k row-major, v transposed
        #pragma unroll
        for (int jt = 0; jt < 6; ++jt) {
            int colL = jt * 16 + ln;
            int seg  = colL >> 5;        // 0=q 1=k 2=v (uniform per jt)
            int cc   = colL & 31;
            float bias = qkv_b[(seg << 8) + (h << 5) + cc];
            #pragma unroll
            for (int r = 0; r < 4; ++r) {
                float v = acc[jt][r] + bias;
                int tok = row0 + r;
                if (seg == 0)      q_s[tok * 40 + cc] = (unsigned short)f2bf(v * 0.17677669529663689f);
                else if (seg == 1) k_s[tok * 40 + cc] = (unsigned short)f2bf(v);
                else               vt_s[cc * 72 + tok] = (unsigned short)f2bf(v);
            }
        }
        __syncthreads();

        // ---- GEMM2: S = q @ k^T  (wave's 16 q-rows x all 64 k-cols), K=32
        short8 aq = *(const short8*)(q_s + (wave * 16 + ln) * 40 + quad * 8);
        f32x4 sacc[4];
        #pragma unroll
        for (int nt = 0; nt < 4; ++nt) {
            short8 bk = *(const short8*)(k_s + (nt * 16 + ln) * 40 + quad * 8);
            f32x4 z = (f32x4){0.f, 0.f, 0.f, 0.f};
            sacc[nt] = __builtin_amdgcn_mfma_f32_16x16x32_bf16(aq, bk, z, 0, 0, 0);
        }
        // bias + shift-mask, computed analytically per element
        float sv[4][4];
        #pragma unroll
        for (int nt = 0; nt < 4; ++nt) {
            int tk = nt * 16 + ln;
            int tik = tk >> 3, tjk = tk & 7;
            int cntk = region(wh * 8 + tik) * 3 + region(ww * 8 + tjk);
            #pragma unroll
            for (int r = 0; r < 4; ++r) {
                int tq = row0 + r;
                int tiq = tq >> 3, tjq = tq & 7;
                int idx = (tiq - tik + 7) * 15 + (tjq - tjk + 7);
                int cntq = region(wh * 8 + tiq) * 3 + region(ww * 8 + tjq);
                float s = sacc[nt][r] + tbl[idx * 8 + h];
                if (cntq != cntk) s -= 100.0f;
                sv[nt][r] = s;
            }
        }
        // softmax: row's 64 values = 16 lanes (this quad) x 4 nt-accums
        #pragma unroll
        for (int r = 0; r < 4; ++r) {
            float m = fmaxf(fmaxf(sv[0][r], sv[1][r]), fmaxf(sv[2][r], sv[3][r]));
            m = fmaxf(m, __shfl_xor(m, 1, 64));
            m = fmaxf(m, __shfl_xor(m, 2, 64));
            m = fmaxf(m, __shfl_xor(m, 4, 64));
            m = fmaxf(m, __shfl_xor(m, 8, 64));
            float p0 = __expf(sv[0][r] - m);
            float p1 = __expf(sv[1][r] - m);
            float p2 = __expf(sv[2][r] - m);
            float p3 = __expf(sv[3][r] - m);
            float ssum = p0 + p1 + p2 + p3;
            ssum += __shfl_xor(ssum, 1, 64);
            ssum += __shfl_xor(ssum, 2, 64);
            ssum += __shfl_xor(ssum, 4, 64);
            ssum += __shfl_xor(ssum, 8, 64);
            float inv = 1.0f / ssum;
            int pr = (row0 + r) * 72;
            p_s[pr +      ln] = (unsigned short)f2bf(p0 * inv);
            p_s[pr + 16 + ln] = (unsigned short)f2bf(p1 * inv);
            p_s[pr + 32 + ln] = (unsigned short)f2bf(p2 * inv);
            p_s[pr + 48 + ln] = (unsigned short)f2bf(p3 * inv);
        }

        // ---- PV: O = P @ V  (16 rows x 32 hd, K=64). Same-wave LDS in-order
        // makes p_s write->read safe without a barrier (rows are wave-private).
        f32x4 oacc[2];
        oacc[0] = (f32x4){0.f, 0.f, 0.f, 0.f};
        oacc[1] = (f32x4){0.f, 0.f, 0.f, 0.f};
        #pragma unroll
        for (int ks = 0; ks < 2; ++ks) {
            short8 ap = *(const short8*)(p_s + (wave * 16 + ln) * 72 + ks * 32 + quad * 8);
            #pragma unroll
            for (int nt = 0; nt < 2; ++nt) {
                short8 bv = *(const short8*)(vt_s + (nt * 16 + ln) * 72 + ks * 32 + quad * 8);
                oacc[nt] = __builtin_amdgcn_mfma_f32_16x16x32_bf16(ap, bv, oacc[nt], 0, 0, 0);
            }
        }
        #pragma unroll
        for (int nt = 0; nt < 2; ++nt)
            #pragma unroll
            for (int r = 0; r < 4; ++r)
                o_s[(row0 + r) * 33 + nt * 16 + ln] = oacc[nt][r];
        __syncthreads();

        // ---- output: thread = (ti2, hd); two float4 stores per thread with
        // the +SHIFT roll folded into addresses (both halves 16B aligned).
        {
            int cl  = tid & 31;          // hd
            int ti2 = tid >> 5;          // 0..7
            f32x4 v0, v1;
            #pragma unroll
            for (int tj = 0; tj < 4; ++tj) v0[tj] = o_s[(ti2 * 8 + tj) * 33 + cl];
            #pragma unroll
            for (int tj = 0; tj < 4; ++tj) v1[tj] = o_s[(ti2 * 8 + 4 + tj) * 33 + cl];
            int c  = (h << 5) + cl;
            int di = (wh * 8 + ti2 + 4) & 63;
            float* op = out + ((size_t)(b * 256 + c)) * 4096 + di * 64;
            *(f32x4*)(op + (ww * 8 + 4))        = v0;
            *(f32x4*)(op + ((ww * 8 + 8) & 63)) = v1;
        }
    }
}

extern "C" void kernel_launch(void* const* d_in, const int* in_sizes, int n_in,
                              void* d_out, int out_size, void* d_ws, size_t ws_size,
                              hipStream_t stream) {
    const float* x      = (const float*)d_in[0];
    const float* qkv_w  = (const float*)d_in[1];
    const float* qkv_b  = (const float*)d_in[2];
    const float* tbl    = (const float*)d_in[3];
    float* out          = (float*)d_out;
    unsigned short* Wt  = (unsigned short*)d_ws;   // needs 768*256*2 = 393216 B

    wt_transpose<<<dim3(768), dim3(256), 0, stream>>>(qkv_w, Wt);
    swin_kernel<<<dim3(2048), dim3(256), 0, stream>>>(x, Wt, qkv_b, tbl, out);
}